// Round 18
// baseline (62.302 us; speedup 1.0000x reference)
//
#include <hip/hip_runtime.h>
#include <hip/hip_bf16.h>
#include <stdint.h>

// PairRelationEncoder: out[b,e,s] = b2[s] + sum_r W2[s,r]*relu(b1[r] + sum_f W1[r,f]*pair[b,e,f])
// pair = [zi, zj, zi-zj, zi*zj] folded to [zi, zj, zi*zj]: Wzi=W1a+W1c, Wzj=W1b-W1c, Wpr=W1d.
// B=4 N=4096 D=64 E=131072 R=64. Out f32 (4,131072,64).
//
// R18: PIPE REBALANCE. R17 verbatim except W2-fragment reads and bias-init reads moved
// from LDS to the prepacked GLOBAL image (8KB w2 + 512B bias are L1-resident; bias reads
// are quarter-wave-uniform -> L1 broadcast). LDS ops/subtile 46 -> 30; LDS = w1 24576 +
// h1 16384 = 40960 B exactly. Zero register/structure delta -- clean isolation of the
// address-space variable. (R16 lesson: NT stores -8.9us, reverted. R17: prefetch null, kept.)

typedef __attribute__((ext_vector_type(8))) __bf16 bf16x8;
typedef __attribute__((ext_vector_type(4))) __bf16 bf16x4;
typedef __attribute__((ext_vector_type(4))) float  f32x4;

#define E_TOT 131072
#define N_TOK 4096
#define ROWS_PER_BLOCK 512
#define NSUB 4   // per wave: 4 subtiles x 16 pairs (8 waves -> 512 rows/block)
#define Z_ELEMS (4 * N_TOK * 64)
#define WIMG_OFF (Z_ELEMS * 2)          // byte offset of weight image in d_ws (after bf16 z)
#define WIMG_B1 32768                   // f32[64]
#define WIMG_B2 33024                   // f32[64]

__device__ __forceinline__ bf16x8 pk8(float4 a, float4 b) {
    bf16x8 r;
    r[0] = (__bf16)a.x; r[1] = (__bf16)a.y; r[2] = (__bf16)a.z; r[3] = (__bf16)a.w;
    r[4] = (__bf16)b.x; r[5] = (__bf16)b.y; r[6] = (__bf16)b.z; r[7] = (__bf16)b.w;
    return r;
}
__device__ __forceinline__ float4 f4add(float4 a, float4 b){ return make_float4(a.x+b.x, a.y+b.y, a.z+b.z, a.w+b.w); }
__device__ __forceinline__ float4 f4sub(float4 a, float4 b){ return make_float4(a.x-b.x, a.y-b.y, a.z-b.z, a.w-b.w); }

// ---- prep: blocks 0..511 cast z f32->bf16; block 512 packs the swizzled weight image ----
__global__ __launch_bounds__(256) void prep_kernel(
    const float* __restrict__ z, const float* __restrict__ W1, const float* __restrict__ b1,
    const float* __restrict__ W2, const float* __restrict__ b2,
    __bf16* __restrict__ zw, char* __restrict__ wimg)
{
    const int tid = threadIdx.x;
    const int blk = blockIdx.x;
    if (blk < 512) {
        const int t = blk * 256 + tid;
        const float4 a = ((const float4*)z)[2 * t];
        const float4 b = ((const float4*)z)[2 * t + 1];
        ((bf16x8*)zw)[t] = pk8(a, b);
        return;
    }
    const int part = tid >> 6;            // 0:zi 1:zj 2:pr 3:W2
    const int scol = tid & 63;
    const int cswz = (scol & 7) << 4;
    if (part < 3) {
        const float* wr = W1 + (size_t)scol * 256;
        char* dst = wimg + scol * 384;
#pragma unroll
        for (int c8 = 0; c8 < 8; ++c8) {
            float4 p0, p1;
            if (part == 0) {
                float4 a0 = *(const float4*)(wr + c8*8);
                float4 a1 = *(const float4*)(wr + c8*8 + 4);
                float4 c0 = *(const float4*)(wr + 128 + c8*8);
                float4 c1 = *(const float4*)(wr + 128 + c8*8 + 4);
                p0 = f4add(a0, c0); p1 = f4add(a1, c1);
            } else if (part == 1) {
                float4 a0 = *(const float4*)(wr + 64 + c8*8);
                float4 a1 = *(const float4*)(wr + 64 + c8*8 + 4);
                float4 c0 = *(const float4*)(wr + 128 + c8*8);
                float4 c1 = *(const float4*)(wr + 128 + c8*8 + 4);
                p0 = f4sub(a0, c0); p1 = f4sub(a1, c1);
            } else {
                p0 = *(const float4*)(wr + 192 + c8*8);
                p1 = *(const float4*)(wr + 192 + c8*8 + 4);
            }
            *(bf16x8*)(dst + ((part * 128 + c8 * 16) ^ cswz)) = pk8(p0, p1);
        }
    } else {
        const float* wr = W2 + (size_t)scol * 64;
        char* dst = wimg + 24576 + scol * 128;
#pragma unroll
        for (int c8 = 0; c8 < 8; ++c8) {
            float4 p0 = *(const float4*)(wr + c8*8);
            float4 p1 = *(const float4*)(wr + c8*8 + 4);
            *(bf16x8*)(dst + ((c8 * 16) ^ cswz)) = pk8(p0, p1);
        }
    }
    if (tid < 64)            *(float*)(wimg + WIMG_B1 + 4 * tid) = b1[tid];
    else if (tid < 128)      *(float*)(wimg + WIMG_B2 + 4 * (tid - 64)) = b2[tid - 64];
}

__device__ __forceinline__ f32x4 mfma16(bf16x8 a, bf16x8 b, f32x4 c) {
    return __builtin_amdgcn_mfma_f32_16x16x32_bf16(a, b, c, 0, 0, 0);
}

__device__ __forceinline__ bf16x8 bmul(bf16x8 a, bf16x8 b) {
    bf16x8 r;
#pragma unroll
    for (int t = 0; t < 8; ++t)
        r[t] = (__bf16)((float)a[t] * (float)b[t]);
    return r;
}

__global__ __launch_bounds__(512, 4) void PairRelationEncoder_62775241998442_kernel(
    const __bf16* __restrict__ zw, const char* __restrict__ wimg,
    const int* __restrict__ pairs, float* __restrict__ out)
{
    const int tid  = threadIdx.x;
    const int wave = tid >> 6;
    const int lane = tid & 63;
    const int x = lane & 15;   // e-index within subtile (B-col / C-col)
    const int g = lane >> 4;   // k-group

    // bijective XCD-chunked swizzle (1024 blocks, 8 XCDs)
    const int bid = (int)(blockIdx.x & 7) * 128 + ((int)blockIdx.x >> 3);
    const int m0 = bid * ROWS_PER_BLOCK;
    const int b  = m0 >> 17;
    const int e0 = m0 & (E_TOT - 1);
    const __bf16* zb = zw + ((size_t)b * N_TOK * 64);

    // hoisted pairs
    int2 ijv[NSUB];
#pragma unroll
    for (int st = 0; st < NSUB; ++st)
        ijv[st] = *(const int2*)(pairs + 2 * (size_t)(e0 + (st * 8 + wave) * 16 + x));

    // LDS: w1 image (24576) + per-wave h1 (8x2048) = 40960 B exactly.
    // W2 + biases stay in the global image (L1-resident).
    __shared__ char   wall[24576];
    __shared__ __bf16 h1s[8][1024];
    __bf16* h1w = h1s[wave];
    const char* w1b = wall;
    const char* w2g = wimg + 24576;                 // global, L1-resident (8 KB)
    const float* bias1 = (const float*)(wimg + WIMG_B1);
    const float* bias2 = (const float*)(wimg + WIMG_B2);

    // ---- staging = pure copy of w1's 24576 B: 3x (float4 load + b128 LDS write) ----
#pragma unroll
    for (int r = 0; r < 3; ++r) {
        const int off = (r * 512 + tid) * 16;
        float4 v = *(const float4*)(wimg + off);
        *(float4*)(wall + off) = v;
    }

    // ---- subtile-0 z prefetch (R17): LDS-independent, hides first gather latency ----
    const __bf16* zri0 = zb + (size_t)ijv[0].x * 64;
    const __bf16* zrj0 = zb + (size_t)ijv[0].y * 64;
    bf16x8 pf_a0 = *(const bf16x8*)(zri0 + g * 8);        // zi h=0
    bf16x8 pf_b0 = *(const bf16x8*)(zrj0 + g * 8);        // zj h=0
    bf16x8 pf_a1 = *(const bf16x8*)(zri0 + 32 + g * 8);   // zi h=1
    bf16x8 pf_b1 = *(const bf16x8*)(zrj0 + 32 + g * 8);   // zj h=1

    __syncthreads();

    const int sw = (x & 7) << 4;

#pragma unroll
    for (int st = 0; st < NSUB; ++st) {
        const __bf16* zri = zb + (size_t)ijv[st].x * 64;
        const __bf16* zrj = zb + (size_t)ijv[st].y * 64;

        // ---- layer 1 (transposed): acc[ct][q] = h1[r=ct*16+g*4+q][e=x], init = b1 (L1) ----
        f32x4 acc[4];
#pragma unroll
        for (int ct = 0; ct < 4; ++ct)
            acc[ct] = *(const f32x4*)(bias1 + ct * 16 + g * 4);

#pragma unroll
        for (int h = 0; h < 2; ++h) {
            // per-h gather (subtile 0 uses the pre-barrier prefetch)
            bf16x8 azf, bzf;
            if (st == 0) { azf = (h == 0) ? pf_a0 : pf_a1; bzf = (h == 0) ? pf_b0 : pf_b1; }
            else {
                azf = *(const bf16x8*)(zri + h * 32 + g * 8);
                bzf = *(const bf16x8*)(zrj + h * 32 + g * 8);
            }
            bf16x8 pzf = bmul(azf, bzf);                            // zi*zj half
            const int kb = h * 64 + g * 16;
#pragma unroll
            for (int ct = 0; ct < 4; ++ct) {
                const int colr = ct * 16 + x;
                const int cswz = (colr & 7) << 4;
                const char* wb = w1b + colr * 384;
                bf16x8 wzi = *(const bf16x8*)(wb + ((kb      ) ^ cswz));
                bf16x8 wzj = *(const bf16x8*)(wb + ((kb + 128) ^ cswz));
                bf16x8 wpr = *(const bf16x8*)(wb + ((kb + 256) ^ cswz));
                acc[ct] = mfma16(wzi, azf, acc[ct]);
                acc[ct] = mfma16(wzj, bzf, acc[ct]);
                acc[ct] = mfma16(wpr, pzf, acc[ct]);
            }
        }

        // ---- epilogue: relu, pack 4xbf16, one ds_write_b64 per ct (wave-private) ----
#pragma unroll
        for (int ct = 0; ct < 4; ++ct) {
            bf16x4 p;
#pragma unroll
            for (int q = 0; q < 4; ++q)
                p[q] = (__bf16)fmaxf(acc[ct][q], 0.f);
            const int wo = (x * 128 + ct * 32 + g * 8) ^ sw;
            *(bf16x4*)((char*)h1w + wo) = p;
        }

        // ---- layer 2 (transposed): o[ct][q] = out[e=x][s=ct*16+g*4+q], init = b2 (L1);
        //      W2 fragments read from the global image (L1-resident, off the LDS pipe) ----
        f32x4 o[4];
#pragma unroll
        for (int ct = 0; ct < 4; ++ct)
            o[ct] = *(const f32x4*)(bias2 + ct * 16 + g * 4);

#pragma unroll
        for (int kk = 0; kk < 2; ++kk) {
            const int aoff = (x * 128 + kk * 64 + g * 16) ^ sw;
            const bf16x8 h1f = *(const bf16x8*)((const char*)h1w + aoff);
#pragma unroll
            for (int ct = 0; ct < 4; ++ct) {
                const int cols = ct * 16 + x;
                const bf16x8 w2f = *(const bf16x8*)(w2g + cols * 128
                                                    + ((kk * 64 + g * 16) ^ ((cols & 7) << 4)));
                o[ct] = mfma16(w2f, h1f, o[ct]);
            }
        }

        // ---- store: 4x global_store_dwordx4 (plain; NT measured -8.9us in R16) ----
        float* orow = out + ((size_t)(m0 + (st * 8 + wave) * 16 + x)) * 64;
#pragma unroll
        for (int ct = 0; ct < 4; ++ct)
            *(f32x4*)(orow + ct * 16 + g * 4) = o[ct];
    }
}

extern "C" void kernel_launch(void* const* d_in, const int* in_sizes, int n_in,
                              void* d_out, int out_size, void* d_ws, size_t ws_size,
                              hipStream_t stream) {
    const float* z     = (const float*)d_in[0];
    const int*   pairs = (const int*)  d_in[1];
    const float* W1    = (const float*)d_in[2];
    const float* b1    = (const float*)d_in[3];
    const float* W2    = (const float*)d_in[4];
    const float* b2    = (const float*)d_in[5];
    float* out = (float*)d_out;
    __bf16* zw  = (__bf16*)d_ws;                   // 2 MB bf16 copy of z
    char*   img = (char*)d_ws + WIMG_OFF;          // 33.3 KB packed weight image + biases

    prep_kernel<<<513, 256, 0, stream>>>(z, W1, b1, W2, b2, zw, img);

    const int total_rows = 4 * E_TOT;              // 524288
    dim3 grid(total_rows / ROWS_PER_BLOCK);        // 1024
    PairRelationEncoder_62775241998442_kernel<<<grid, 512, 0, stream>>>(
        zw, img, pairs, out);
}

// Round 19
// 46.033 us; speedup vs baseline: 1.3534x; 1.3534x over previous
//
#include <hip/hip_runtime.h>
#include <hip/hip_bf16.h>
#include <stdint.h>

// PairRelationEncoder: out[b,e,s] = b2[s] + sum_r W2[s,r]*relu(b1[r] + sum_f W1[r,f]*pair[b,e,f])
// pair = [zi, zj, zi-zj, zi*zj] folded to [zi, zj, zi*zj]: Wzi=W1a+W1c, Wzj=W1b-W1c, Wpr=W1d.
// B=4 N=4096 D=64 E=131072 R=64. Out f32 (4,131072,64).
//
// R19: CLEAN E-UNROLL x2. R11's e-unroll was confounded by bias-in-registers (+32 live VGPR
// -> spills); here it's isolated on R14's config (512 thr, 2 blocks/CU, biases in LDS).
// Each weight fragment read feeds TWO 16-pair subtiles: LDS ops per 2 subtiles 92 -> 52
// (weights 48->24+8, bias shared 16->8). Peak live ~99 regs < 128 cap. LDS 66048B ->
// still 2 blocks/CU, 16 waves. (R16: NT stores -8.9us. R18: W2-from-global -17us. Both reverted.)

typedef __attribute__((ext_vector_type(8))) __bf16 bf16x8;
typedef __attribute__((ext_vector_type(4))) __bf16 bf16x4;
typedef __attribute__((ext_vector_type(4))) float  f32x4;

#define E_TOT 131072
#define N_TOK 4096
#define ROWS_PER_BLOCK 512
#define NSUB 4   // per wave: 4 subtiles x 16 pairs (8 waves -> 512 rows/block)
#define Z_ELEMS (4 * N_TOK * 64)
#define WIMG_OFF (Z_ELEMS * 2)          // byte offset of weight image in d_ws (after bf16 z)
#define WIMG_B1 32768                   // f32[64]
#define WIMG_B2 33024                   // f32[64]

__device__ __forceinline__ bf16x8 pk8(float4 a, float4 b) {
    bf16x8 r;
    r[0] = (__bf16)a.x; r[1] = (__bf16)a.y; r[2] = (__bf16)a.z; r[3] = (__bf16)a.w;
    r[4] = (__bf16)b.x; r[5] = (__bf16)b.y; r[6] = (__bf16)b.z; r[7] = (__bf16)b.w;
    return r;
}
__device__ __forceinline__ float4 f4add(float4 a, float4 b){ return make_float4(a.x+b.x, a.y+b.y, a.z+b.z, a.w+b.w); }
__device__ __forceinline__ float4 f4sub(float4 a, float4 b){ return make_float4(a.x-b.x, a.y-b.y, a.z-b.z, a.w-b.w); }

// ---- prep: blocks 0..511 cast z f32->bf16; block 512 packs the swizzled weight image ----
__global__ __launch_bounds__(256) void prep_kernel(
    const float* __restrict__ z, const float* __restrict__ W1, const float* __restrict__ b1,
    const float* __restrict__ W2, const float* __restrict__ b2,
    __bf16* __restrict__ zw, char* __restrict__ wimg)
{
    const int tid = threadIdx.x;
    const int blk = blockIdx.x;
    if (blk < 512) {
        const int t = blk * 256 + tid;
        const float4 a = ((const float4*)z)[2 * t];
        const float4 b = ((const float4*)z)[2 * t + 1];
        ((bf16x8*)zw)[t] = pk8(a, b);
        return;
    }
    const int part = tid >> 6;            // 0:zi 1:zj 2:pr 3:W2
    const int scol = tid & 63;
    const int cswz = (scol & 7) << 4;
    if (part < 3) {
        const float* wr = W1 + (size_t)scol * 256;
        char* dst = wimg + scol * 384;
#pragma unroll
        for (int c8 = 0; c8 < 8; ++c8) {
            float4 p0, p1;
            if (part == 0) {
                float4 a0 = *(const float4*)(wr + c8*8);
                float4 a1 = *(const float4*)(wr + c8*8 + 4);
                float4 c0 = *(const float4*)(wr + 128 + c8*8);
                float4 c1 = *(const float4*)(wr + 128 + c8*8 + 4);
                p0 = f4add(a0, c0); p1 = f4add(a1, c1);
            } else if (part == 1) {
                float4 a0 = *(const float4*)(wr + 64 + c8*8);
                float4 a1 = *(const float4*)(wr + 64 + c8*8 + 4);
                float4 c0 = *(const float4*)(wr + 128 + c8*8);
                float4 c1 = *(const float4*)(wr + 128 + c8*8 + 4);
                p0 = f4sub(a0, c0); p1 = f4sub(a1, c1);
            } else {
                p0 = *(const float4*)(wr + 192 + c8*8);
                p1 = *(const float4*)(wr + 192 + c8*8 + 4);
            }
            *(bf16x8*)(dst + ((part * 128 + c8 * 16) ^ cswz)) = pk8(p0, p1);
        }
    } else {
        const float* wr = W2 + (size_t)scol * 64;
        char* dst = wimg + 24576 + scol * 128;
#pragma unroll
        for (int c8 = 0; c8 < 8; ++c8) {
            float4 p0 = *(const float4*)(wr + c8*8);
            float4 p1 = *(const float4*)(wr + c8*8 + 4);
            *(bf16x8*)(dst + ((c8 * 16) ^ cswz)) = pk8(p0, p1);
        }
    }
    if (tid < 64)            *(float*)(wimg + WIMG_B1 + 4 * tid) = b1[tid];
    else if (tid < 128)      *(float*)(wimg + WIMG_B2 + 4 * (tid - 64)) = b2[tid - 64];
}

__device__ __forceinline__ f32x4 mfma16(bf16x8 a, bf16x8 b, f32x4 c) {
    return __builtin_amdgcn_mfma_f32_16x16x32_bf16(a, b, c, 0, 0, 0);
}

__device__ __forceinline__ bf16x8 bmul(bf16x8 a, bf16x8 b) {
    bf16x8 r;
#pragma unroll
    for (int t = 0; t < 8; ++t)
        r[t] = (__bf16)((float)a[t] * (float)b[t]);
    return r;
}

__global__ __launch_bounds__(512, 4) void PairRelationEncoder_62775241998442_kernel(
    const __bf16* __restrict__ zw, const char* __restrict__ wimg,
    const int* __restrict__ pairs, float* __restrict__ out)
{
    const int tid  = threadIdx.x;
    const int wave = tid >> 6;
    const int lane = tid & 63;
    const int x = lane & 15;   // e-index within subtile (B-col / C-col)
    const int g = lane >> 4;   // k-group

    // bijective XCD-chunked swizzle (1024 blocks, 8 XCDs)
    const int bid = (int)(blockIdx.x & 7) * 128 + ((int)blockIdx.x >> 3);
    const int m0 = bid * ROWS_PER_BLOCK;
    const int b  = m0 >> 17;
    const int e0 = m0 & (E_TOT - 1);
    const __bf16* zb = zw + ((size_t)b * N_TOK * 64);

    // hoisted pairs
    int2 ijv[NSUB];
#pragma unroll
    for (int st = 0; st < NSUB; ++st)
        ijv[st] = *(const int2*)(pairs + 2 * (size_t)(e0 + (st * 8 + wave) * 16 + x));

    // LDS: weight image (32768) + per-wave h1 x2 subtiles (8x4096) + biases (512) = 66048 B
    // -> 2 blocks/CU; 16 waves/CU at VGPR<=128.
    __shared__ char   wall[32768];
    __shared__ __bf16 h1s[8][2048];
    __shared__ float  b1s[64];
    __shared__ float  b2s[64];
    __bf16* h1A = h1s[wave];
    __bf16* h1B = h1s[wave] + 1024;
    const char* w1b = wall;
    const char* w2b = wall + 24576;

    // ---- staging = pure copy of the prepacked image: 4x (float4 load + b128 LDS write) ----
#pragma unroll
    for (int r = 0; r < 4; ++r) {
        const int off = (r * 512 + tid) * 16;
        float4 v = *(const float4*)(wimg + off);
        *(float4*)(wall + off) = v;
    }
    if (tid < 64)            b1s[tid] = *(const float*)(wimg + WIMG_B1 + 4 * tid);
    else if (tid < 128)      b2s[tid - 64] = *(const float*)(wimg + WIMG_B2 + 4 * (tid - 64));

    __syncthreads();

    const int sw = (x & 7) << 4;

#pragma unroll
    for (int sup = 0; sup < 2; ++sup) {
        const int stA = 2 * sup, stB = 2 * sup + 1;
        const __bf16* zriA = zb + (size_t)ijv[stA].x * 64;
        const __bf16* zrjA = zb + (size_t)ijv[stA].y * 64;
        const __bf16* zriB = zb + (size_t)ijv[stB].x * 64;
        const __bf16* zrjB = zb + (size_t)ijv[stB].y * 64;

        // ---- layer 1 (transposed), TWO subtiles per weight read; bias read once, shared ----
        f32x4 accA[4], accB[4];
#pragma unroll
        for (int ct = 0; ct < 4; ++ct) {
            f32x4 bv = *(const f32x4*)(b1s + ct * 16 + g * 4);
            accA[ct] = bv; accB[ct] = bv;
        }

#pragma unroll
        for (int h = 0; h < 2; ++h) {
            bf16x8 azfA = *(const bf16x8*)(zriA + h * 32 + g * 8);
            bf16x8 bzfA = *(const bf16x8*)(zrjA + h * 32 + g * 8);
            bf16x8 pzfA = bmul(azfA, bzfA);
            bf16x8 azfB = *(const bf16x8*)(zriB + h * 32 + g * 8);
            bf16x8 bzfB = *(const bf16x8*)(zrjB + h * 32 + g * 8);
            bf16x8 pzfB = bmul(azfB, bzfB);
            const int kb = h * 64 + g * 16;
#pragma unroll
            for (int ct = 0; ct < 4; ++ct) {
                const int colr = ct * 16 + x;
                const int cswz = (colr & 7) << 4;
                const char* wb = w1b + colr * 384;
                bf16x8 wzi = *(const bf16x8*)(wb + ((kb      ) ^ cswz));
                bf16x8 wzj = *(const bf16x8*)(wb + ((kb + 128) ^ cswz));
                bf16x8 wpr = *(const bf16x8*)(wb + ((kb + 256) ^ cswz));
                accA[ct] = mfma16(wzi, azfA, accA[ct]);
                accB[ct] = mfma16(wzi, azfB, accB[ct]);
                accA[ct] = mfma16(wzj, bzfA, accA[ct]);
                accB[ct] = mfma16(wzj, bzfB, accB[ct]);
                accA[ct] = mfma16(wpr, pzfA, accA[ct]);
                accB[ct] = mfma16(wpr, pzfB, accB[ct]);
            }
        }

        // ---- epilogue: relu, pack, one ds_write_b64 per ct per subtile (wave-private) ----
#pragma unroll
        for (int ct = 0; ct < 4; ++ct) {
            bf16x4 pA, pB;
#pragma unroll
            for (int q = 0; q < 4; ++q) {
                pA[q] = (__bf16)fmaxf(accA[ct][q], 0.f);
                pB[q] = (__bf16)fmaxf(accB[ct][q], 0.f);
            }
            const int wo = (x * 128 + ct * 32 + g * 8) ^ sw;
            *(bf16x4*)((char*)h1A + wo) = pA;
            *(bf16x4*)((char*)h1B + wo) = pB;
        }

        // ---- layer 2 (transposed), TWO subtiles per W2 read; bias read once, shared ----
        f32x4 oA[4], oB[4];
#pragma unroll
        for (int ct = 0; ct < 4; ++ct) {
            f32x4 bv = *(const f32x4*)(b2s + ct * 16 + g * 4);
            oA[ct] = bv; oB[ct] = bv;
        }

#pragma unroll
        for (int kk = 0; kk < 2; ++kk) {
            const int aoff = (x * 128 + kk * 64 + g * 16) ^ sw;
            const bf16x8 h1fA = *(const bf16x8*)((const char*)h1A + aoff);
            const bf16x8 h1fB = *(const bf16x8*)((const char*)h1B + aoff);
#pragma unroll
            for (int ct = 0; ct < 4; ++ct) {
                const int cols = ct * 16 + x;
                const bf16x8 w2f = *(const bf16x8*)(w2b + cols * 128
                                                    + ((kk * 64 + g * 16) ^ ((cols & 7) << 4)));
                oA[ct] = mfma16(w2f, h1fA, oA[ct]);
                oB[ct] = mfma16(w2f, h1fB, oB[ct]);
            }
        }

        // ---- store: 4x global_store_dwordx4 per subtile (plain; NT = -8.9us in R16) ----
        float* orowA = out + ((size_t)(m0 + (stA * 8 + wave) * 16 + x)) * 64;
        float* orowB = out + ((size_t)(m0 + (stB * 8 + wave) * 16 + x)) * 64;
#pragma unroll
        for (int ct = 0; ct < 4; ++ct) {
            *(f32x4*)(orowA + ct * 16 + g * 4) = oA[ct];
            *(f32x4*)(orowB + ct * 16 + g * 4) = oB[ct];
        }
    }
}

extern "C" void kernel_launch(void* const* d_in, const int* in_sizes, int n_in,
                              void* d_out, int out_size, void* d_ws, size_t ws_size,
                              hipStream_t stream) {
    const float* z     = (const float*)d_in[0];
    const int*   pairs = (const int*)  d_in[1];
    const float* W1    = (const float*)d_in[2];
    const float* b1    = (const float*)d_in[3];
    const float* W2    = (const float*)d_in[4];
    const float* b2    = (const float*)d_in[5];
    float* out = (float*)d_out;
    __bf16* zw  = (__bf16*)d_ws;                   // 2 MB bf16 copy of z
    char*   img = (char*)d_ws + WIMG_OFF;          // 33.3 KB packed weight image + biases

    prep_kernel<<<513, 256, 0, stream>>>(z, W1, b1, W2, b2, zw, img);

    const int total_rows = 4 * E_TOT;              // 524288
    dim3 grid(total_rows / ROWS_PER_BLOCK);        // 1024
    PairRelationEncoder_62775241998442_kernel<<<grid, 512, 0, stream>>>(
        zw, img, pairs, out);
}

// Round 20
// 45.244 us; speedup vs baseline: 1.3770x; 1.0174x over previous
//
#include <hip/hip_runtime.h>
#include <hip/hip_bf16.h>
#include <stdint.h>

// PairRelationEncoder: out[b,e,s] = b2[s] + sum_r W2[s,r]*relu(b1[r] + sum_f W1[r,f]*pair[b,e,f])
// pair = [zi, zj, zi-zj, zi*zj] folded to [zi, zj, zi*zj]: Wzi=W1a+W1c, Wzj=W1b-W1c, Wpr=W1d.
// B=4 N=4096 D=64 E=131072 R=64. Out f32 (4,131072,64).
//
// R20 = R14 VERBATIM (session best, 45.28us). Final config after 19 measured rounds:
//   - prep kernel: z f32->bf16 (2MB) + weight fold/pack/swizzle to a 33KB global image (R10, -5.5us)
//   - main: 512thr/8 waves, NSUB=4, grid 1024, 16 waves/CU (R14, -2.4us), XCD-chunked swizzle
//   - 16x16 MFMA transposed dataflow, LDS weights, per-wave h1 roundtrip, bias LDS broadcast
// Measured nulls/regressions (documented, reverted): LDS-traffic cuts (R11/R19 null),
// 32x32 reg-handoff body (R13 -5), NSUB=8 (R15 -7, reg spills), NT stores (R16 -8.9),
// z-prefetch (R17 null), W2-from-global (R18 -17, TA scatter >> LDS pipe).
// Plateau: 2.0x composite HBM floor (~23us), latency-bound at the 16-wave/CU occupancy
// ceiling (VGPR>64 -> 4 waves/SIMD; LDS 49.7KB -> 2 blocks/CU). No pipe >60%.

typedef __attribute__((ext_vector_type(8))) __bf16 bf16x8;
typedef __attribute__((ext_vector_type(4))) __bf16 bf16x4;
typedef __attribute__((ext_vector_type(4))) float  f32x4;

#define E_TOT 131072
#define N_TOK 4096
#define ROWS_PER_BLOCK 512
#define NSUB 4   // per wave: 4 subtiles x 16 pairs (8 waves -> 512 rows/block)
#define Z_ELEMS (4 * N_TOK * 64)
#define WIMG_OFF (Z_ELEMS * 2)          // byte offset of weight image in d_ws (after bf16 z)
#define WIMG_B1 32768                   // f32[64]
#define WIMG_B2 33024                   // f32[64]

__device__ __forceinline__ bf16x8 pk8(float4 a, float4 b) {
    bf16x8 r;
    r[0] = (__bf16)a.x; r[1] = (__bf16)a.y; r[2] = (__bf16)a.z; r[3] = (__bf16)a.w;
    r[4] = (__bf16)b.x; r[5] = (__bf16)b.y; r[6] = (__bf16)b.z; r[7] = (__bf16)b.w;
    return r;
}
__device__ __forceinline__ float4 f4add(float4 a, float4 b){ return make_float4(a.x+b.x, a.y+b.y, a.z+b.z, a.w+b.w); }
__device__ __forceinline__ float4 f4sub(float4 a, float4 b){ return make_float4(a.x-b.x, a.y-b.y, a.z-b.z, a.w-b.w); }

// ---- prep: blocks 0..511 cast z f32->bf16; block 512 packs the swizzled weight image ----
__global__ __launch_bounds__(256) void prep_kernel(
    const float* __restrict__ z, const float* __restrict__ W1, const float* __restrict__ b1,
    const float* __restrict__ W2, const float* __restrict__ b2,
    __bf16* __restrict__ zw, char* __restrict__ wimg)
{
    const int tid = threadIdx.x;
    const int blk = blockIdx.x;
    if (blk < 512) {
        const int t = blk * 256 + tid;
        const float4 a = ((const float4*)z)[2 * t];
        const float4 b = ((const float4*)z)[2 * t + 1];
        ((bf16x8*)zw)[t] = pk8(a, b);
        return;
    }
    const int part = tid >> 6;            // 0:zi 1:zj 2:pr 3:W2
    const int scol = tid & 63;
    const int cswz = (scol & 7) << 4;
    if (part < 3) {
        const float* wr = W1 + (size_t)scol * 256;
        char* dst = wimg + scol * 384;
#pragma unroll
        for (int c8 = 0; c8 < 8; ++c8) {
            float4 p0, p1;
            if (part == 0) {
                float4 a0 = *(const float4*)(wr + c8*8);
                float4 a1 = *(const float4*)(wr + c8*8 + 4);
                float4 c0 = *(const float4*)(wr + 128 + c8*8);
                float4 c1 = *(const float4*)(wr + 128 + c8*8 + 4);
                p0 = f4add(a0, c0); p1 = f4add(a1, c1);
            } else if (part == 1) {
                float4 a0 = *(const float4*)(wr + 64 + c8*8);
                float4 a1 = *(const float4*)(wr + 64 + c8*8 + 4);
                float4 c0 = *(const float4*)(wr + 128 + c8*8);
                float4 c1 = *(const float4*)(wr + 128 + c8*8 + 4);
                p0 = f4sub(a0, c0); p1 = f4sub(a1, c1);
            } else {
                p0 = *(const float4*)(wr + 192 + c8*8);
                p1 = *(const float4*)(wr + 192 + c8*8 + 4);
            }
            *(bf16x8*)(dst + ((part * 128 + c8 * 16) ^ cswz)) = pk8(p0, p1);
        }
    } else {
        const float* wr = W2 + (size_t)scol * 64;
        char* dst = wimg + 24576 + scol * 128;
#pragma unroll
        for (int c8 = 0; c8 < 8; ++c8) {
            float4 p0 = *(const float4*)(wr + c8*8);
            float4 p1 = *(const float4*)(wr + c8*8 + 4);
            *(bf16x8*)(dst + ((c8 * 16) ^ cswz)) = pk8(p0, p1);
        }
    }
    if (tid < 64)            *(float*)(wimg + WIMG_B1 + 4 * tid) = b1[tid];
    else if (tid < 128)      *(float*)(wimg + WIMG_B2 + 4 * (tid - 64)) = b2[tid - 64];
}

__device__ __forceinline__ f32x4 mfma16(bf16x8 a, bf16x8 b, f32x4 c) {
    return __builtin_amdgcn_mfma_f32_16x16x32_bf16(a, b, c, 0, 0, 0);
}

__device__ __forceinline__ bf16x8 bmul(bf16x8 a, bf16x8 b) {
    bf16x8 r;
#pragma unroll
    for (int t = 0; t < 8; ++t)
        r[t] = (__bf16)((float)a[t] * (float)b[t]);
    return r;
}

__global__ __launch_bounds__(512, 4) void PairRelationEncoder_62775241998442_kernel(
    const __bf16* __restrict__ zw, const char* __restrict__ wimg,
    const int* __restrict__ pairs, float* __restrict__ out)
{
    const int tid  = threadIdx.x;
    const int wave = tid >> 6;
    const int lane = tid & 63;
    const int x = lane & 15;   // e-index within subtile (B-col / C-col)
    const int g = lane >> 4;   // k-group

    // bijective XCD-chunked swizzle (1024 blocks, 8 XCDs)
    const int bid = (int)(blockIdx.x & 7) * 128 + ((int)blockIdx.x >> 3);
    const int m0 = bid * ROWS_PER_BLOCK;
    const int b  = m0 >> 17;
    const int e0 = m0 & (E_TOT - 1);
    const __bf16* zb = zw + ((size_t)b * N_TOK * 64);

    // hoisted pairs
    int2 ijv[NSUB];
#pragma unroll
    for (int st = 0; st < NSUB; ++st)
        ijv[st] = *(const int2*)(pairs + 2 * (size_t)(e0 + (st * 8 + wave) * 16 + x));

    // LDS: weight image (32768) + per-wave h1 (8x2048) + biases (512) = 49664 B
    // -> 2 blocks/CU (LDS); 16 waves/CU at VGPR<=128.
    __shared__ char   wall[32768];
    __shared__ __bf16 h1s[8][1024];
    __shared__ float  b1s[64];
    __shared__ float  b2s[64];
    __bf16* h1w = h1s[wave];
    const char* w1b = wall;
    const char* w2b = wall + 24576;

    // ---- staging = pure copy of the prepacked image: 4x (float4 load + b128 LDS write) ----
#pragma unroll
    for (int r = 0; r < 4; ++r) {
        const int off = (r * 512 + tid) * 16;
        float4 v = *(const float4*)(wimg + off);
        *(float4*)(wall + off) = v;
    }
    if (tid < 64)            b1s[tid] = *(const float*)(wimg + WIMG_B1 + 4 * tid);
    else if (tid < 128)      b2s[tid - 64] = *(const float*)(wimg + WIMG_B2 + 4 * (tid - 64));

    __syncthreads();

    const int sw = (x & 7) << 4;

#pragma unroll
    for (int st = 0; st < NSUB; ++st) {
        const __bf16* zri = zb + (size_t)ijv[st].x * 64;
        const __bf16* zrj = zb + (size_t)ijv[st].y * 64;

        // ---- layer 1 (transposed): acc[ct][q] = h1[r=ct*16+g*4+q][e=x], init = b1 ----
        f32x4 acc[4];
#pragma unroll
        for (int ct = 0; ct < 4; ++ct)
            acc[ct] = *(const f32x4*)(b1s + ct * 16 + g * 4);

#pragma unroll
        for (int h = 0; h < 2; ++h) {
            // per-h JIT gather: 3 live frags (12 regs)
            bf16x8 azf = *(const bf16x8*)(zri + h * 32 + g * 8);   // zi half
            bf16x8 bzf = *(const bf16x8*)(zrj + h * 32 + g * 8);   // zj half
            bf16x8 pzf = bmul(azf, bzf);                            // zi*zj half
            const int kb = h * 64 + g * 16;
#pragma unroll
            for (int ct = 0; ct < 4; ++ct) {
                const int colr = ct * 16 + x;
                const int cswz = (colr & 7) << 4;
                const char* wb = w1b + colr * 384;
                bf16x8 wzi = *(const bf16x8*)(wb + ((kb      ) ^ cswz));
                bf16x8 wzj = *(const bf16x8*)(wb + ((kb + 128) ^ cswz));
                bf16x8 wpr = *(const bf16x8*)(wb + ((kb + 256) ^ cswz));
                acc[ct] = mfma16(wzi, azf, acc[ct]);
                acc[ct] = mfma16(wzj, bzf, acc[ct]);
                acc[ct] = mfma16(wpr, pzf, acc[ct]);
            }
        }

        // ---- epilogue: relu, pack 4xbf16, one ds_write_b64 per ct (wave-private) ----
#pragma unroll
        for (int ct = 0; ct < 4; ++ct) {
            bf16x4 p;
#pragma unroll
            for (int q = 0; q < 4; ++q)
                p[q] = (__bf16)fmaxf(acc[ct][q], 0.f);
            const int wo = (x * 128 + ct * 32 + g * 8) ^ sw;
            *(bf16x4*)((char*)h1w + wo) = p;
        }

        // ---- layer 2 (transposed): o[ct][q] = out[e=x][s=ct*16+g*4+q], init = b2 ----
        f32x4 o[4];
#pragma unroll
        for (int ct = 0; ct < 4; ++ct)
            o[ct] = *(const f32x4*)(b2s + ct * 16 + g * 4);

#pragma unroll
        for (int kk = 0; kk < 2; ++kk) {
            const int aoff = (x * 128 + kk * 64 + g * 16) ^ sw;
            const bf16x8 h1f = *(const bf16x8*)((const char*)h1w + aoff);
#pragma unroll
            for (int ct = 0; ct < 4; ++ct) {
                const int cols = ct * 16 + x;
                const bf16x8 w2f = *(const bf16x8*)(w2b + cols * 128
                                                    + ((kk * 64 + g * 16) ^ ((cols & 7) << 4)));
                o[ct] = mfma16(w2f, h1f, o[ct]);
            }
        }

        // ---- store: 4x global_store_dwordx4 ----
        float* orow = out + ((size_t)(m0 + (st * 8 + wave) * 16 + x)) * 64;
#pragma unroll
        for (int ct = 0; ct < 4; ++ct)
            *(f32x4*)(orow + ct * 16 + g * 4) = o[ct];
    }
}

extern "C" void kernel_launch(void* const* d_in, const int* in_sizes, int n_in,
                              void* d_out, int out_size, void* d_ws, size_t ws_size,
                              hipStream_t stream) {
    const float* z     = (const float*)d_in[0];
    const int*   pairs = (const int*)  d_in[1];
    const float* W1    = (const float*)d_in[2];
    const float* b1    = (const float*)d_in[3];
    const float* W2    = (const float*)d_in[4];
    const float* b2    = (const float*)d_in[5];
    float* out = (float*)d_out;
    __bf16* zw  = (__bf16*)d_ws;                   // 2 MB bf16 copy of z
    char*   img = (char*)d_ws + WIMG_OFF;          // 33.3 KB packed weight image + biases

    prep_kernel<<<513, 256, 0, stream>>>(z, W1, b1, W2, b2, zw, img);

    const int total_rows = 4 * E_TOT;              // 524288
    dim3 grid(total_rows / ROWS_PER_BLOCK);        // 1024
    PairRelationEncoder_62775241998442_kernel<<<grid, 512, 0, stream>>>(
        zw, img, pairs, out);
}